// Round 10
// baseline (51.846 us; speedup 1.0000x reference)
//
#include <hip/hip_runtime.h>
#include <math.h>

#define NTHR 256
#define K_FINE 2048
#define HW 147456          // 384*384
#define N1 1179648         // 8*HW
#define IMG 384
#define NHC 16             // hist chunks per batch
#define NCHUNK 128         // 8*16
#define NTILE 1152         // 8 * 144 ssim tiles
#define TOTAL (NTILE + NCHUNK)   // 1280 = 256 CUs * 5 blocks
#define NSOFT 256

// ws word offsets
#define WS_PMM  0                       // [3][256][2] floats (min,max partials)
#define WS_SUM  1536                    // [3][256] floats: Sxd, Sx, Sd partials
#define WS_CTR  2304                    // ticket (8 ints)
#define WS_HIST 2312                    // 8*2048 ints (global atomic hist)
#define WS_SSIM (WS_HIST + 8*K_FINE)    // 1152 floats
#define WS_UNIF (WS_SSIM + NTILE)       // 256 floats

#define HRS (42*33)
#define SMEMF (5*HRS)                   // 6930 floats = 27.7 KB (5 hr planes)

// ================= K1: min/max + raw-sum partials; zero hist+ticket =========
__global__ __launch_bounds__(NTHR) void k_minmax(
        const float* __restrict__ x, const float* __restrict__ tg,
        const float* __restrict__ dp, float* __restrict__ wsf)
{
    __shared__ float swred[4][12];
    const int tid = threadIdx.x, bid = blockIdx.x;
    const float4* x4 = (const float4*)x  + bid * 1152;
    const float4* t4 = (const float4*)tg + bid * 1152;
    const float4* d4 = (const float4*)dp + bid * 1152;
    float mn0 = 3.4e38f, mx0 = -3.4e38f;
    float mn1 = 3.4e38f, mx1 = -3.4e38f;
    float mn2 = 3.4e38f, mx2 = -3.4e38f;
    float sx = 0.f, sd = 0.f, sxd = 0.f;
    for (int i = tid; i < 1152; i += NTHR) {
        float4 a = x4[i], b = t4[i], d = d4[i];
        mn0 = fminf(mn0, fminf(fminf(a.x, a.y), fminf(a.z, a.w)));
        mx0 = fmaxf(mx0, fmaxf(fmaxf(a.x, a.y), fmaxf(a.z, a.w)));
        mn1 = fminf(mn1, fminf(fminf(b.x, b.y), fminf(b.z, b.w)));
        mx1 = fmaxf(mx1, fmaxf(fmaxf(b.x, b.y), fmaxf(b.z, b.w)));
        mn2 = fminf(mn2, fminf(fminf(d.x, d.y), fminf(d.z, d.w)));
        mx2 = fmaxf(mx2, fmaxf(fmaxf(d.x, d.y), fmaxf(d.z, d.w)));
        sx += (a.x + a.y) + (a.z + a.w);
        sd += (d.x + d.y) + (d.z + d.w);
        sxd = fmaf(a.x, d.x, fmaf(a.y, d.y, fmaf(a.z, d.z, fmaf(a.w, d.w, sxd))));
    }
    #pragma unroll
    for (int off = 32; off; off >>= 1) {
        mn0 = fminf(mn0, __shfl_down(mn0, off, 64));
        mx0 = fmaxf(mx0, __shfl_down(mx0, off, 64));
        mn1 = fminf(mn1, __shfl_down(mn1, off, 64));
        mx1 = fmaxf(mx1, __shfl_down(mx1, off, 64));
        mn2 = fminf(mn2, __shfl_down(mn2, off, 64));
        mx2 = fmaxf(mx2, __shfl_down(mx2, off, 64));
        sx  += __shfl_down(sx,  off, 64);
        sd  += __shfl_down(sd,  off, 64);
        sxd += __shfl_down(sxd, off, 64);
    }
    if ((tid & 63) == 0) {
        int w = tid >> 6;
        swred[w][0] = mn0; swred[w][1] = mx0; swred[w][2] = mn1;
        swred[w][3] = mx1; swred[w][4] = mn2; swred[w][5] = mx2;
        swred[w][6] = sxd; swred[w][7] = sx;  swred[w][8] = sd;
    }
    __syncthreads();
    if (tid == 0) {
        #pragma unroll
        for (int w = 1; w < 4; w++) {
            swred[0][0] = fminf(swred[0][0], swred[w][0]);
            swred[0][1] = fmaxf(swred[0][1], swred[w][1]);
            swred[0][2] = fminf(swred[0][2], swred[w][2]);
            swred[0][3] = fmaxf(swred[0][3], swred[w][3]);
            swred[0][4] = fminf(swred[0][4], swred[w][4]);
            swred[0][5] = fmaxf(swred[0][5], swred[w][5]);
            swred[0][6] += swred[w][6];
            swred[0][7] += swred[w][7];
            swred[0][8] += swred[w][8];
        }
        wsf[WS_PMM +        bid * 2]     = swred[0][0];
        wsf[WS_PMM +        bid * 2 + 1] = swred[0][1];
        wsf[WS_PMM + 512  + bid * 2]     = swred[0][2];
        wsf[WS_PMM + 512  + bid * 2 + 1] = swred[0][3];
        wsf[WS_PMM + 1024 + bid * 2]     = swred[0][4];
        wsf[WS_PMM + 1024 + bid * 2 + 1] = swred[0][5];
        wsf[WS_SUM +        bid] = swred[0][6];
        wsf[WS_SUM + 256  + bid] = swred[0][7];
        wsf[WS_SUM + 512  + bid] = swred[0][8];
        if (bid == 0) ((int*)wsf)[WS_CTR] = 0;
    }
    if (tid < 64) ((int*)wsf)[WS_HIST + bid * 64 + tid] = 0;
}

// helper: per-block redundant global min/max reduce from partials
__device__ __forceinline__ void reduce_minmax(
        const float* __restrict__ wsf, float swred[4][12], int tid,
        float& xmn, float& xinv, float& tmn, float& tinv, float& dmn, float& dinv)
{
    const float2* pm = (const float2*)&wsf[WS_PMM];
    float2 a = pm[tid], b = pm[256 + tid], c = pm[512 + tid];
    float mn0 = a.x, mx0 = a.y, mn1 = b.x, mx1 = b.y, mn2 = c.x, mx2 = c.y;
    #pragma unroll
    for (int off = 32; off; off >>= 1) {
        mn0 = fminf(mn0, __shfl_down(mn0, off, 64));
        mx0 = fmaxf(mx0, __shfl_down(mx0, off, 64));
        mn1 = fminf(mn1, __shfl_down(mn1, off, 64));
        mx1 = fmaxf(mx1, __shfl_down(mx1, off, 64));
        mn2 = fminf(mn2, __shfl_down(mn2, off, 64));
        mx2 = fmaxf(mx2, __shfl_down(mx2, off, 64));
    }
    if ((tid & 63) == 0) {
        int w = tid >> 6;
        swred[w][0] = mn0; swred[w][1] = mx0; swred[w][2] = mn1;
        swred[w][3] = mx1; swred[w][4] = mn2; swred[w][5] = mx2;
    }
    __syncthreads();
    mn0 = fminf(fminf(swred[0][0], swred[1][0]), fminf(swred[2][0], swred[3][0]));
    mx0 = fmaxf(fmaxf(swred[0][1], swred[1][1]), fmaxf(swred[2][1], swred[3][1]));
    mn1 = fminf(fminf(swred[0][2], swred[1][2]), fminf(swred[2][2], swred[3][2]));
    mx1 = fmaxf(fmaxf(swred[0][3], swred[1][3]), fmaxf(swred[2][3], swred[3][3]));
    mn2 = fminf(fminf(swred[0][4], swred[1][4]), fminf(swred[2][4], swred[3][4]));
    mx2 = fmaxf(fmaxf(swred[0][5], swred[1][5]), fmaxf(swred[2][5], swred[3][5]));
    xmn = mn0; xinv = 1.0f / (mx0 - mn0);
    tmn = mn1; tinv = 1.0f / (mx1 - mn1);
    dmn = mn2; dinv = 1.0f / (mx2 - mn2);
    __syncthreads();
}

// ================= K2: fused SSIM tiles + hist chunks =======================
__global__ __launch_bounds__(NTHR) void k_work(
        const float* __restrict__ x, const float* __restrict__ tg,
        float* __restrict__ wsf)
{
    __shared__ float smem[SMEMF];
    __shared__ float swred[4][12];
    const int tid = threadIdx.x, bid = blockIdx.x;

    float xmn, xinv, tmn, tinv, dmn, dinv;
    reduce_minmax(wsf, swred, tid, xmn, xinv, tmn, tinv, dmn, dinv);
    (void)dmn; (void)dinv;

    if (bid < NTILE) {
        // -------- SSIM tile: 2 barriers, direct-global horiz, 5ch fused ----
        float g[11];
        {
            float s = 0.f;
            #pragma unroll
            for (int i = 0; i < 11; i++) {
                float dd = (float)(i - 5);
                g[i] = expf(-dd * dd / 4.5f);
                s += g[i];
            }
            float is = 1.0f / s;
            #pragma unroll
            for (int i = 0; i < 11; i++) g[i] *= is;
        }
        float* hr0 = smem;             // [42][33] x5
        float* hr1 = hr0 + HRS;
        float* hr2 = hr1 + HRS;
        float* hr3 = hr2 + HRS;
        float* hr4 = hr3 + HRS;
        int img = bid / 144;
        int tl  = bid % 144;
        int ty0 = (tl / 12) * 32 - 5;
        int tx0 = (tl % 12) * 32 - 5;
        const float* xb = x  + (size_t)img * HW;
        const float* tb = tg + (size_t)img * HW;

        // horizontal pass: all 5 channels, inputs direct from global/L1
        for (int t = tid; t < 42 * 33; t += NTHR) {
            int rr = t / 33, cx = t - rr * 33;
            int gy = ty0 + rr, b = tx0 + cx;
            float o[11], ii[11];
            bool rowOK = ((unsigned)gy < (unsigned)IMG);
            if (rowOK && b >= 0 && b + 10 < IMG) {
                const float* po = xb + gy * IMG + b;
                const float* pi = tb + gy * IMG + b;
                #pragma unroll
                for (int k = 0; k < 11; k++) {
                    o[k]  = (po[k] - xmn) * xinv;
                    ii[k] = (pi[k] - tmn) * tinv;
                }
            } else {
                #pragma unroll
                for (int k = 0; k < 11; k++) {
                    int gx = b + k;
                    bool okk = rowOK && ((unsigned)gx < (unsigned)IMG);
                    float xv = 0.f, tv = 0.f;
                    if (okk) {
                        int off = gy * IMG + gx;
                        xv = (xb[off] - xmn) * xinv;
                        tv = (tb[off] - tmn) * tinv;
                    }
                    o[k] = xv; ii[k] = tv;
                }
            }
            float c1 = 0, c2 = 0, c3 = 0, c4 = 0, c5 = 0;
            #pragma unroll
            for (int k = 0; k < 11; k++) {
                float gk = g[k];
                float go = gk * o[k], gi = gk * ii[k];
                c1 = fmaf(gk, o[k], c1);
                c2 = fmaf(gk, ii[k], c2);
                c3 = fmaf(go, o[k], c3);
                c4 = fmaf(gi, ii[k], c4);
                c5 = fmaf(go, ii[k], c5);
            }
            hr0[t] = c1; hr1[t] = c2; hr2[t] = c3; hr3[t] = c4; hr4[t] = c5;
        }
        __syncthreads();

        // vertical pass: per-channel streaming (static indexing, low VGPR)
        const int ox = tid & 31, oy0 = (tid >> 5) << 2;
        float a1[4], a2[4], b11[4], b22[4], b12[4];
        #define VCONV(HR, ACC)                                              \
        {                                                                   \
            float w[14];                                                    \
            _Pragma("unroll")                                               \
            for (int k = 0; k < 14; k++) w[k] = HR[(oy0 + k) * 33 + ox];    \
            _Pragma("unroll")                                               \
            for (int p = 0; p < 4; p++) {                                   \
                float m = 0.f;                                              \
                _Pragma("unroll")                                           \
                for (int dy = 0; dy < 11; dy++) m = fmaf(g[dy], w[p + dy], m); \
                ACC[p] = m;                                                 \
            }                                                               \
        }
        VCONV(hr0, a1) VCONV(hr1, a2) VCONV(hr2, b11) VCONV(hr3, b22) VCONV(hr4, b12)
        #undef VCONV

        const float C1 = 1e-4f, C2 = 9e-4f;
        float lsum = 0.f;
        #pragma unroll
        for (int p = 0; p < 4; p++) {
            float mu1s = a1[p] * a1[p], mu2s = a2[p] * a2[p];
            float mu12 = a1[p] * a2[p];
            float s1 = b11[p] - mu1s, s2 = b22[p] - mu2s, s12 = b12[p] - mu12;
            lsum += ((2.f * mu12 + C1) * (2.f * s12 + C2))
                  / ((mu1s + mu2s + C1) * (s1 + s2 + C2));
        }
        #pragma unroll
        for (int off = 32; off; off >>= 1) lsum += __shfl_down(lsum, off, 64);
        if ((tid & 63) == 0) swred[tid >> 6][6] = lsum;
        __syncthreads();
        if (tid == 0)
            wsf[WS_SSIM + bid] = swred[0][6] + swred[1][6] + swred[2][6] + swred[3][6];
    } else {
        // -------- hist chunk (x only; depth folded into k_minmax) --------
        int c = bid - NTILE;
        int* lh = (int*)smem;
        for (int i = tid; i < K_FINE; i += NTHR) lh[i] = 0;
        __syncthreads();
        int batch = c >> 4, chunk = c & 15;
        const float4* x4 = (const float4*)x + (size_t)batch * (HW / 4) + chunk * 2304;
        for (int i = tid; i < 2304; i += NTHR) {
            float4 xv = x4[i];
            float o0 = (xv.x - xmn) * xinv, o1 = (xv.y - xmn) * xinv;
            float o2 = (xv.z - xmn) * xinv, o3 = (xv.w - xmn) * xinv;
            int j0 = min(K_FINE - 1, max(0, (int)(o0 * K_FINE)));
            int j1 = min(K_FINE - 1, max(0, (int)(o1 * K_FINE)));
            int j2 = min(K_FINE - 1, max(0, (int)(o2 * K_FINE)));
            int j3 = min(K_FINE - 1, max(0, (int)(o3 * K_FINE)));
            atomicAdd(lh + j0, 1); atomicAdd(lh + j1, 1);
            atomicAdd(lh + j2, 1); atomicAdd(lh + j3, 1);
        }
        __syncthreads();
        int* gh = (int*)wsf + WS_HIST + batch * K_FINE;
        for (int i = tid; i < K_FINE; i += NTHR) {
            int v = lh[i];
            if (v) atomicAdd(gh + i, v);
        }
    }
}

// ================= K3: soft-hist entropy + last-block final combine =========
__global__ __launch_bounds__(NTHR) void k_soft_final(
        float* __restrict__ wsf, float* __restrict__ out)
{
    __shared__ int lh[K_FINE];
    __shared__ float swred[4][12];
    __shared__ float s8[8];
    __shared__ int amLast;
    const int tid = threadIdx.x, bid = blockIdx.x;
    int batch = bid >> 5;
    const int* gh = (const int*)wsf + WS_HIST + batch * K_FINE;
    for (int i = tid; i < K_FINE; i += NTHR) lh[i] = gh[i];
    __syncthreads();
    int binLocal = tid >> 5, slice = tid & 31;
    int bin = (bid & 31) * 8 + binLocal;
    const float delta = 1.0f / 256.0f;
    const float r   = expf(3.0f * delta);
    const float rm1 = r - 1.0f;
    const float c32 = expf(-3.0f * 32.0f / (float)K_FINE);
    float L = (float)bin * delta;
    float u = expf(3.0f * (L - ((float)slice + 0.5f) * (1.0f / (float)K_FINE)));
    float h = 0.f;
    #pragma unroll 4
    for (int j = slice; j < K_FINE; j += 32) {
        float cnt = (float)lh[j];
        float t1 = 1.0f + u;
        float t2 = fmaf(u, r, 1.0f);
        h = fmaf(cnt * (u * rm1), __builtin_amdgcn_rcpf(t1 * t2), h);
        u *= c32;
    }
    #pragma unroll
    for (int off = 16; off; off >>= 1) h += __shfl_down(h, off, 32);
    if (slice == 0) s8[binLocal] = h;
    __syncthreads();
    if (tid == 0) {
        float hl = 0.f;
        #pragma unroll
        for (int b = 0; b < 8; b++) {
            float hh = s8[b];
            hl += (hh > 0.f) ? hh * logf(hh) : 0.f;
        }
        wsf[WS_UNIF + bid] = hl;
        __threadfence();
        int old = atomicAdd((int*)wsf + WS_CTR, 1);
        amLast = (old == NSOFT - 1);
    }
    __syncthreads();
    if (!amLast) return;

    // ---- final combine (last softhist finisher) ----
    __threadfence();  // acquire: all UNIF partials visible
    float xmn, xinv, tmn, tinv, dmn, dinv;
    reduce_minmax(wsf, swred, tid, xmn, xinv, tmn, tinv, dmn, dinv);
    (void)tmn; (void)tinv;
    float sxd  = wsf[WS_SUM + tid];
    float sx   = wsf[WS_SUM + 256 + tid];
    float sd   = wsf[WS_SUM + 512 + tid];
    float bsum = 0.f;
    for (int i = tid; i < NTILE; i += NTHR) bsum += wsf[WS_SSIM + i];
    float c = wsf[WS_UNIF + tid];
    float* r0 = (float*)lh;          // 5*256 floats fit in lh (2048 words)
    float* r1 = r0 + 256; float* r2 = r1 + 256;
    float* r3 = r2 + 256; float* r4 = r3 + 256;
    r0[tid] = sxd; r1[tid] = sx; r2[tid] = sd; r3[tid] = bsum; r4[tid] = c;
    __syncthreads();
    for (int s = 128; s; s >>= 1) {
        if (tid < s) {
            r0[tid] += r0[tid + s]; r1[tid] += r1[tid + s];
            r2[tid] += r2[tid + s]; r3[tid] += r3[tid + s];
            r4[tid] += r4[tid + s];
        }
        __syncthreads();
    }
    if (tid == 0) {
        float SXD = r0[0], SX = r1[0], SD = r2[0];
        float uniform  = r4[0] / 8.0f;
        float depthNum = SXD - xmn * SD - dmn * SX + (float)N1 * xmn * dmn;
        float depthL   = xinv * dinv * depthNum / 8.0f;
        float ssimMean = r3[0] / (float)N1;
        out[0] = 1e-6f * uniform + 1e-5f * depthL + (1.0f - ssimMean);
    }
}

extern "C" void kernel_launch(void* const* d_in, const int* in_sizes, int n_in,
                              void* d_out, int out_size, void* d_ws, size_t ws_size,
                              hipStream_t stream) {
    const float* x  = (const float*)d_in[0];
    const float* tg = (const float*)d_in[1];
    const float* dp = (const float*)d_in[2];
    float* wsf = (float*)d_ws;
    float* out = (float*)d_out;
    hipLaunchKernelGGL(k_minmax,     dim3(256),   dim3(NTHR), 0, stream, x, tg, dp, wsf);
    hipLaunchKernelGGL(k_work,       dim3(TOTAL), dim3(NTHR), 0, stream, x, tg, wsf);
    hipLaunchKernelGGL(k_soft_final, dim3(NSOFT), dim3(NTHR), 0, stream, wsf, out);
}

// Round 11
// 42.030 us; speedup vs baseline: 1.2335x; 1.2335x over previous
//
#include <hip/hip_runtime.h>
#include <math.h>

#define NTHR 256
#define WTHR 512
#define K_FINE 2048
#define HW 147456          // 384*384
#define N1 1179648         // 8*HW
#define IMG 384
#define NCHUNK 128         // 8*16 hist chunks
#define NTILE 1152         // 8 * 144 ssim tiles
#define TOTAL (NTILE + NCHUNK)   // 1280 blocks
#define NSOFT 256

// ws word offsets
#define WS_PMM  0                       // [3][256][2] floats (min,max partials)
#define WS_SUM  1536                    // [3][256] floats: Sxd, Sx, Sd partials
#define WS_CTR  2304                    // ticket (8 ints)
#define WS_HIST 2312                    // 8*2048 ints (global atomic hist)
#define WS_SSIM (WS_HIST + 8*K_FINE)    // 1152 floats
#define WS_UNIF (WS_SSIM + NTILE)       // 256 floats

#define HRS (42*33)
#define SMEMF (42*43*2 + 3*HRS)         // 7770 floats = 31.1 KB

// ================= K1: min/max + raw-sum partials; zero hist+ticket =========
__global__ __launch_bounds__(NTHR) void k_minmax(
        const float* __restrict__ x, const float* __restrict__ tg,
        const float* __restrict__ dp, float* __restrict__ wsf)
{
    __shared__ float swred[4][12];
    const int tid = threadIdx.x, bid = blockIdx.x;
    const float4* x4 = (const float4*)x  + bid * 1152;
    const float4* t4 = (const float4*)tg + bid * 1152;
    const float4* d4 = (const float4*)dp + bid * 1152;
    float mn0 = 3.4e38f, mx0 = -3.4e38f;
    float mn1 = 3.4e38f, mx1 = -3.4e38f;
    float mn2 = 3.4e38f, mx2 = -3.4e38f;
    float sx = 0.f, sd = 0.f, sxd = 0.f;
    for (int i = tid; i < 1152; i += NTHR) {
        float4 a = x4[i], b = t4[i], d = d4[i];
        mn0 = fminf(mn0, fminf(fminf(a.x, a.y), fminf(a.z, a.w)));
        mx0 = fmaxf(mx0, fmaxf(fmaxf(a.x, a.y), fmaxf(a.z, a.w)));
        mn1 = fminf(mn1, fminf(fminf(b.x, b.y), fminf(b.z, b.w)));
        mx1 = fmaxf(mx1, fmaxf(fmaxf(b.x, b.y), fmaxf(b.z, b.w)));
        mn2 = fminf(mn2, fminf(fminf(d.x, d.y), fminf(d.z, d.w)));
        mx2 = fmaxf(mx2, fmaxf(fmaxf(d.x, d.y), fmaxf(d.z, d.w)));
        sx += (a.x + a.y) + (a.z + a.w);
        sd += (d.x + d.y) + (d.z + d.w);
        sxd = fmaf(a.x, d.x, fmaf(a.y, d.y, fmaf(a.z, d.z, fmaf(a.w, d.w, sxd))));
    }
    #pragma unroll
    for (int off = 32; off; off >>= 1) {
        mn0 = fminf(mn0, __shfl_down(mn0, off, 64));
        mx0 = fmaxf(mx0, __shfl_down(mx0, off, 64));
        mn1 = fminf(mn1, __shfl_down(mn1, off, 64));
        mx1 = fmaxf(mx1, __shfl_down(mx1, off, 64));
        mn2 = fminf(mn2, __shfl_down(mn2, off, 64));
        mx2 = fmaxf(mx2, __shfl_down(mx2, off, 64));
        sx  += __shfl_down(sx,  off, 64);
        sd  += __shfl_down(sd,  off, 64);
        sxd += __shfl_down(sxd, off, 64);
    }
    if ((tid & 63) == 0) {
        int w = tid >> 6;
        swred[w][0] = mn0; swred[w][1] = mx0; swred[w][2] = mn1;
        swred[w][3] = mx1; swred[w][4] = mn2; swred[w][5] = mx2;
        swred[w][6] = sxd; swred[w][7] = sx;  swred[w][8] = sd;
    }
    __syncthreads();
    if (tid == 0) {
        #pragma unroll
        for (int w = 1; w < 4; w++) {
            swred[0][0] = fminf(swred[0][0], swred[w][0]);
            swred[0][1] = fmaxf(swred[0][1], swred[w][1]);
            swred[0][2] = fminf(swred[0][2], swred[w][2]);
            swred[0][3] = fmaxf(swred[0][3], swred[w][3]);
            swred[0][4] = fminf(swred[0][4], swred[w][4]);
            swred[0][5] = fmaxf(swred[0][5], swred[w][5]);
            swred[0][6] += swred[w][6];
            swred[0][7] += swred[w][7];
            swred[0][8] += swred[w][8];
        }
        wsf[WS_PMM +        bid * 2]     = swred[0][0];
        wsf[WS_PMM +        bid * 2 + 1] = swred[0][1];
        wsf[WS_PMM + 512  + bid * 2]     = swred[0][2];
        wsf[WS_PMM + 512  + bid * 2 + 1] = swred[0][3];
        wsf[WS_PMM + 1024 + bid * 2]     = swred[0][4];
        wsf[WS_PMM + 1024 + bid * 2 + 1] = swred[0][5];
        wsf[WS_SUM +        bid] = swred[0][6];
        wsf[WS_SUM + 256  + bid] = swred[0][7];
        wsf[WS_SUM + 512  + bid] = swred[0][8];
        if (bid == 0) ((int*)wsf)[WS_CTR] = 0;
    }
    if (tid < 64) ((int*)wsf)[WS_HIST + bid * 64 + tid] = 0;
}

// helper: per-block redundant global min/max reduce (works for any blockDim;
// threads >=256 duplicate partials — harmless for min/max)
template<int NW>
__device__ __forceinline__ void reduce_minmax_t(
        const float* __restrict__ wsf, float swred[NW][12], int tid,
        float& xmn, float& xinv, float& tmn, float& tinv, float& dmn, float& dinv)
{
    const float2* pm = (const float2*)&wsf[WS_PMM];
    int i = tid & 255;
    float2 a = pm[i], b = pm[256 + i], c = pm[512 + i];
    float mn0 = a.x, mx0 = a.y, mn1 = b.x, mx1 = b.y, mn2 = c.x, mx2 = c.y;
    #pragma unroll
    for (int off = 32; off; off >>= 1) {
        mn0 = fminf(mn0, __shfl_down(mn0, off, 64));
        mx0 = fmaxf(mx0, __shfl_down(mx0, off, 64));
        mn1 = fminf(mn1, __shfl_down(mn1, off, 64));
        mx1 = fmaxf(mx1, __shfl_down(mx1, off, 64));
        mn2 = fminf(mn2, __shfl_down(mn2, off, 64));
        mx2 = fmaxf(mx2, __shfl_down(mx2, off, 64));
    }
    if ((tid & 63) == 0) {
        int w = tid >> 6;
        swred[w][0] = mn0; swred[w][1] = mx0; swred[w][2] = mn1;
        swred[w][3] = mx1; swred[w][4] = mn2; swred[w][5] = mx2;
    }
    __syncthreads();
    mn0 = swred[0][0]; mx0 = swred[0][1]; mn1 = swred[0][2];
    mx1 = swred[0][3]; mn2 = swred[0][4]; mx2 = swred[0][5];
    #pragma unroll
    for (int w = 1; w < NW; w++) {
        mn0 = fminf(mn0, swred[w][0]); mx0 = fmaxf(mx0, swred[w][1]);
        mn1 = fminf(mn1, swred[w][2]); mx1 = fmaxf(mx1, swred[w][3]);
        mn2 = fminf(mn2, swred[w][4]); mx2 = fmaxf(mx2, swred[w][5]);
    }
    xmn = mn0; xinv = 1.0f / (mx0 - mn0);
    tmn = mn1; tinv = 1.0f / (mx1 - mn1);
    dmn = mn2; dinv = 1.0f / (mx2 - mn2);
    __syncthreads();
}

// ================= K2: fused SSIM tiles + hist chunks (512 thr, 32 waves/CU) =
__global__ __launch_bounds__(WTHR, 8) void k_work(
        const float* __restrict__ x, const float* __restrict__ tg,
        float* __restrict__ wsf)
{
    __shared__ float smem[SMEMF];
    __shared__ float swred[8][12];
    const int tid = threadIdx.x, bid = blockIdx.x;

    float xmn, xinv, tmn, tinv, dmn, dinv;
    reduce_minmax_t<8>(wsf, swred, tid, xmn, xinv, tmn, tinv, dmn, dinv);
    (void)dmn; (void)dinv;

    if (bid < NTILE) {
        // -------- SSIM tile (32x32 out, 42x42 halo, two-pass moments) ------
        float g[11];
        {
            float s = 0.f;
            #pragma unroll
            for (int i = 0; i < 11; i++) {
                float dd = (float)(i - 5);
                g[i] = expf(-dd * dd / 4.5f);
                s += g[i];
            }
            float is = 1.0f / s;
            #pragma unroll
            for (int i = 0; i < 11; i++) g[i] *= is;
        }
        float* sO  = smem;                 // [42][43]
        float* sI  = smem + 42 * 43;
        float* hr0 = smem + 2 * 42 * 43;   // [42][33] x3
        float* hr1 = hr0 + HRS;
        float* hr2 = hr1 + HRS;
        int img = bid / 144;
        int tl  = bid % 144;
        int ty0 = (tl / 12) * 32 - 5;
        int tx0 = (tl % 12) * 32 - 5;
        const float* xb = x  + (size_t)img * HW;
        const float* tb = tg + (size_t)img * HW;
        for (int idx = tid; idx < 42 * 42; idx += WTHR) {
            int rr = idx / 42, cc = idx % 42;
            int gy = ty0 + rr, gx = tx0 + cc;
            float xv = 0.f, tv = 0.f;
            if (gy >= 0 && gy < IMG && gx >= 0 && gx < IMG) {
                int o = gy * IMG + gx;
                xv = (xb[o] - xmn) * xinv;
                tv = (tb[o] - tmn) * tinv;
            }
            sO[rr * 43 + cc] = xv; sI[rr * 43 + cc] = tv;
        }
        __syncthreads();
        // pass A horiz: mu channels
        for (int t = tid; t < 42 * 32; t += WTHR) {
            int rr = t >> 5, cx = t & 31;
            const float* rowO = sO + rr * 43 + cx;
            const float* rowI = sI + rr * 43 + cx;
            float so = 0, si = 0;
            #pragma unroll
            for (int d = 0; d < 11; d++) { so = fmaf(g[d], rowO[d], so); si = fmaf(g[d], rowI[d], si); }
            hr0[rr * 33 + cx] = so; hr1[rr * 33 + cx] = si;
        }
        __syncthreads();
        // pass A vert: mu1/mu2 into registers (2-row strip per thread)
        const int ox = tid & 31, oy0 = (tid >> 5) << 1;
        float mu1[2], mu2[2];
        {
            float w0[12], w1[12];
            #pragma unroll
            for (int k = 0; k < 12; k++) {
                int hb = (oy0 + k) * 33 + ox;
                w0[k] = hr0[hb]; w1[k] = hr1[hb];
            }
            #pragma unroll
            for (int p = 0; p < 2; p++) {
                float m1 = 0, m2 = 0;
                #pragma unroll
                for (int dy = 0; dy < 11; dy++) {
                    m1 = fmaf(g[dy], w0[p + dy], m1);
                    m2 = fmaf(g[dy], w1[p + dy], m2);
                }
                mu1[p] = m1; mu2[p] = m2;
            }
        }
        __syncthreads();
        // pass B horiz: second moments
        for (int t = tid; t < 42 * 32; t += WTHR) {
            int rr = t >> 5, cx = t & 31;
            const float* rowO = sO + rr * 43 + cx;
            const float* rowI = sI + rr * 43 + cx;
            float soo = 0, sii = 0, soi = 0;
            #pragma unroll
            for (int d = 0; d < 11; d++) {
                float o = rowO[d], ii = rowI[d], w = g[d];
                soo = fmaf(w * o, o, soo); sii = fmaf(w * ii, ii, sii); soi = fmaf(w * o, ii, soi);
            }
            int hb = rr * 33 + cx;
            hr0[hb] = soo; hr1[hb] = sii; hr2[hb] = soi;
        }
        __syncthreads();
        // pass B vert (per-channel streaming) + formula
        float b11[2], b22[2], b12[2];
        #define VCONV(HR, ACC)                                                 \
        {                                                                      \
            float w[12];                                                       \
            _Pragma("unroll")                                                  \
            for (int k = 0; k < 12; k++) w[k] = HR[(oy0 + k) * 33 + ox];       \
            _Pragma("unroll")                                                  \
            for (int p = 0; p < 2; p++) {                                      \
                float m = 0.f;                                                 \
                _Pragma("unroll")                                              \
                for (int dy = 0; dy < 11; dy++) m = fmaf(g[dy], w[p + dy], m); \
                ACC[p] = m;                                                    \
            }                                                                  \
        }
        VCONV(hr0, b11) VCONV(hr1, b22) VCONV(hr2, b12)
        #undef VCONV
        const float C1 = 1e-4f, C2 = 9e-4f;
        float lsum = 0.f;
        #pragma unroll
        for (int p = 0; p < 2; p++) {
            float mu1s = mu1[p] * mu1[p], mu2s = mu2[p] * mu2[p];
            float mu12 = mu1[p] * mu2[p];
            float s1 = b11[p] - mu1s, s2 = b22[p] - mu2s, s12 = b12[p] - mu12;
            lsum += ((2.f * mu12 + C1) * (2.f * s12 + C2))
                  / ((mu1s + mu2s + C1) * (s1 + s2 + C2));
        }
        #pragma unroll
        for (int off = 32; off; off >>= 1) lsum += __shfl_down(lsum, off, 64);
        if ((tid & 63) == 0) swred[tid >> 6][6] = lsum;
        __syncthreads();
        if (tid == 0) {
            float s = 0.f;
            #pragma unroll
            for (int w = 0; w < 8; w++) s += swred[w][6];
            wsf[WS_SSIM + bid] = s;
        }
    } else {
        // -------- hist chunk (x only; depth folded into k_minmax) --------
        int c = bid - NTILE;
        int* lh = (int*)smem;
        for (int i = tid; i < K_FINE; i += WTHR) lh[i] = 0;
        __syncthreads();
        int batch = c >> 4, chunk = c & 15;
        const float4* x4 = (const float4*)x + (size_t)batch * (HW / 4) + chunk * 2304;
        for (int i = tid; i < 2304; i += WTHR) {
            float4 xv = x4[i];
            float o0 = (xv.x - xmn) * xinv, o1 = (xv.y - xmn) * xinv;
            float o2 = (xv.z - xmn) * xinv, o3 = (xv.w - xmn) * xinv;
            int j0 = min(K_FINE - 1, max(0, (int)(o0 * K_FINE)));
            int j1 = min(K_FINE - 1, max(0, (int)(o1 * K_FINE)));
            int j2 = min(K_FINE - 1, max(0, (int)(o2 * K_FINE)));
            int j3 = min(K_FINE - 1, max(0, (int)(o3 * K_FINE)));
            atomicAdd(lh + j0, 1); atomicAdd(lh + j1, 1);
            atomicAdd(lh + j2, 1); atomicAdd(lh + j3, 1);
        }
        __syncthreads();
        int* gh = (int*)wsf + WS_HIST + batch * K_FINE;
        for (int i = tid; i < K_FINE; i += WTHR) {
            int v = lh[i];
            if (v) atomicAdd(gh + i, v);
        }
    }
}

// ================= K3: soft-hist entropy + last-block final combine =========
__global__ __launch_bounds__(NTHR) void k_soft_final(
        float* __restrict__ wsf, float* __restrict__ out)
{
    __shared__ int lh[K_FINE];
    __shared__ float swred[4][12];
    __shared__ float s8[8];
    __shared__ int amLast;
    const int tid = threadIdx.x, bid = blockIdx.x;
    int batch = bid >> 5;
    const int* gh = (const int*)wsf + WS_HIST + batch * K_FINE;
    for (int i = tid; i < K_FINE; i += NTHR) lh[i] = gh[i];
    __syncthreads();
    int binLocal = tid >> 5, slice = tid & 31;
    int bin = (bid & 31) * 8 + binLocal;
    const float delta = 1.0f / 256.0f;
    const float r   = expf(3.0f * delta);
    const float rm1 = r - 1.0f;
    const float c32 = expf(-3.0f * 32.0f / (float)K_FINE);
    float L = (float)bin * delta;
    float u = expf(3.0f * (L - ((float)slice + 0.5f) * (1.0f / (float)K_FINE)));
    float h = 0.f;
    #pragma unroll 4
    for (int j = slice; j < K_FINE; j += 32) {
        float cnt = (float)lh[j];
        float t1 = 1.0f + u;
        float t2 = fmaf(u, r, 1.0f);
        h = fmaf(cnt * (u * rm1), __builtin_amdgcn_rcpf(t1 * t2), h);
        u *= c32;
    }
    #pragma unroll
    for (int off = 16; off; off >>= 1) h += __shfl_down(h, off, 32);
    if (slice == 0) s8[binLocal] = h;
    __syncthreads();
    if (tid == 0) {
        float hl = 0.f;
        #pragma unroll
        for (int b = 0; b < 8; b++) {
            float hh = s8[b];
            hl += (hh > 0.f) ? hh * logf(hh) : 0.f;
        }
        wsf[WS_UNIF + bid] = hl;
        __threadfence();
        int old = atomicAdd((int*)wsf + WS_CTR, 1);
        amLast = (old == NSOFT - 1);
    }
    __syncthreads();
    if (!amLast) return;

    // ---- final combine (last softhist finisher) ----
    __threadfence();  // acquire: all UNIF partials visible
    float xmn, xinv, tmn, tinv, dmn, dinv;
    reduce_minmax_t<4>(wsf, swred, tid, xmn, xinv, tmn, tinv, dmn, dinv);
    (void)tmn; (void)tinv;
    float sxd  = wsf[WS_SUM + tid];
    float sx   = wsf[WS_SUM + 256 + tid];
    float sd   = wsf[WS_SUM + 512 + tid];
    float bsum = 0.f;
    for (int i = tid; i < NTILE; i += NTHR) bsum += wsf[WS_SSIM + i];
    float c = wsf[WS_UNIF + tid];
    float* r0 = (float*)lh;          // 5*256 floats fit in lh (2048 words)
    float* r1 = r0 + 256; float* r2 = r1 + 256;
    float* r3 = r2 + 256; float* r4 = r3 + 256;
    r0[tid] = sxd; r1[tid] = sx; r2[tid] = sd; r3[tid] = bsum; r4[tid] = c;
    __syncthreads();
    for (int s = 128; s; s >>= 1) {
        if (tid < s) {
            r0[tid] += r0[tid + s]; r1[tid] += r1[tid + s];
            r2[tid] += r2[tid + s]; r3[tid] += r3[tid + s];
            r4[tid] += r4[tid + s];
        }
        __syncthreads();
    }
    if (tid == 0) {
        float SXD = r0[0], SX = r1[0], SD = r2[0];
        float uniform  = r4[0] / 8.0f;
        float depthNum = SXD - xmn * SD - dmn * SX + (float)N1 * xmn * dmn;
        float depthL   = xinv * dinv * depthNum / 8.0f;
        float ssimMean = r3[0] / (float)N1;
        out[0] = 1e-6f * uniform + 1e-5f * depthL + (1.0f - ssimMean);
    }
}

extern "C" void kernel_launch(void* const* d_in, const int* in_sizes, int n_in,
                              void* d_out, int out_size, void* d_ws, size_t ws_size,
                              hipStream_t stream) {
    const float* x  = (const float*)d_in[0];
    const float* tg = (const float*)d_in[1];
    const float* dp = (const float*)d_in[2];
    float* wsf = (float*)d_ws;
    float* out = (float*)d_out;
    hipLaunchKernelGGL(k_minmax,     dim3(256),   dim3(NTHR), 0, stream, x, tg, dp, wsf);
    hipLaunchKernelGGL(k_work,       dim3(TOTAL), dim3(WTHR), 0, stream, x, tg, wsf);
    hipLaunchKernelGGL(k_soft_final, dim3(NSOFT), dim3(NTHR), 0, stream, wsf, out);
}